// Round 4
// baseline (667.756 us; speedup 1.0000x reference)
//
#include <hip/hip_runtime.h>
#include <math.h>

// ---------------------------------------------------------------------------
// MapleAttention decode block, fp32, MI355X.
// B=16 tokens, HID=4096, H=32 q-heads, HKV=8 kv-heads (GQA G=4), D=128,
// partial RoPE on first 64 dims, sliding window 1024, paged KV pool.
// Memory-bound: 96MB qkv weights + 64MB wo + ~117MB gathered KV.
// ---------------------------------------------------------------------------

#define NB      16      // batch
#define HID_    4096
#define NH      32      // q heads
#define NKV     8       // kv heads
#define GQ      4       // q heads per kv head
#define DD      128     // head dim
#define ROPE_D  64
#define WIN     1024
#define MAXCTX_ 4096
#define QKV_ROWS 6144   // 4096 q + 1024 k + 1024 v
#define HS      8       // h-split for GEMV kernels
#define NSPLIT  8       // kv-split for attention
#define SCALE_  0.08838834764831845f  // 1/sqrt(128)

// ---------------------------------------------------------------------------
// K1: fused QKV projection.  out[b][o] = dot(hidden[b,:], W[o,:])
// Thread t -> b = t&15, oq = t>>4; owns rows o0+oq+16r, r=0..3.
// Grid (96 row-blocks, HS h-chunks).  Partials to ws.
// Weight addresses are identical across the 16 lanes sharing an oq ->
// broadcast-coalesced; hidden is L2-resident (256KB).
// Issue math: ~37 SIMD-cyc per wave-iter moving 256B unique weight bytes
// -> ~17 TB/s issue-supported >> 6.3 TB/s HBM: stays memory-bound.
// ---------------------------------------------------------------------------
__global__ __launch_bounds__(256) void qkv_gemv(
    const float* __restrict__ hidden,
    const float* __restrict__ wq, const float* __restrict__ wk,
    const float* __restrict__ wv,
    float* __restrict__ qkv_part)
{
    const int rb = blockIdx.x;          // 0..95
    const int hs = blockIdx.y;          // 0..HS-1
    const int t  = threadIdx.x;
    const int b  = t & 15;
    const int oq = t >> 4;              // 0..15
    const int o0 = rb * 64;

    const float* base; int ro;
    if (o0 < 4096)      { base = wq; ro = o0; }
    else if (o0 < 5120) { base = wk; ro = o0 - 4096; }
    else                { base = wv; ro = o0 - 5120; }

    const int h0 = hs * (HID_ / HS);    // 512-wide chunk
    const float4* hp = (const float4*)(hidden + (size_t)b * HID_ + h0);
    const float4* w0 = (const float4*)(base + (size_t)(ro + oq) * HID_ + h0);
    const int rstride = 16 * HID_ / 4;  // +16 rows, in float4 units

    float a0 = 0.f, a1 = 0.f, a2 = 0.f, a3 = 0.f;
    #pragma unroll 4
    for (int i = 0; i < (HID_ / HS) / 4; ++i) {
        float4 hv = hp[i];
        float4 wv0 = w0[i];
        float4 wv1 = w0[i + rstride];
        float4 wv2 = w0[i + 2 * rstride];
        float4 wv3 = w0[i + 3 * rstride];
        a0 = fmaf(hv.x, wv0.x, a0); a0 = fmaf(hv.y, wv0.y, a0);
        a0 = fmaf(hv.z, wv0.z, a0); a0 = fmaf(hv.w, wv0.w, a0);
        a1 = fmaf(hv.x, wv1.x, a1); a1 = fmaf(hv.y, wv1.y, a1);
        a1 = fmaf(hv.z, wv1.z, a1); a1 = fmaf(hv.w, wv1.w, a1);
        a2 = fmaf(hv.x, wv2.x, a2); a2 = fmaf(hv.y, wv2.y, a2);
        a2 = fmaf(hv.z, wv2.z, a2); a2 = fmaf(hv.w, wv2.w, a2);
        a3 = fmaf(hv.x, wv3.x, a3); a3 = fmaf(hv.y, wv3.y, a3);
        a3 = fmaf(hv.z, wv3.z, a3); a3 = fmaf(hv.w, wv3.w, a3);
    }
    float* out = qkv_part + ((size_t)hs * NB + b) * QKV_ROWS + o0 + oq;
    out[0]  = a0;
    out[16] = a1;
    out[32] = a2;
    out[48] = a3;
}

// ---------------------------------------------------------------------------
// K2: sum h-partials, RMSNorm (q,k), partial RoPE (q,k), scatter k/v to pools,
// write normed q to ws.  One wave per (b, unit): unit 0..31 q-head,
// 32..39 k-head, 40..47 v-head.  Lane holds d = {2*lane, 2*lane+1}.
// ---------------------------------------------------------------------------
__global__ __launch_bounds__(64) void norm_rope_scatter(
    const float* __restrict__ qkv_part,
    const float* __restrict__ cosb, const float* __restrict__ sinb,
    const float* __restrict__ qw, const float* __restrict__ kw,
    const int* __restrict__ out_cache_loc,
    float* __restrict__ q_ws,
    float* __restrict__ k_pool, float* __restrict__ v_pool)
{
    const int b    = blockIdx.x;
    const int u    = blockIdx.y;        // 0..47
    const int lane = threadIdx.x;
    const int d0   = lane * 2;

    int row0;
    if (u < 32)      row0 = u * DD;
    else if (u < 40) row0 = 4096 + (u - 32) * DD;
    else             row0 = 5120 + (u - 40) * DD;

    float x0 = 0.f, x1 = 0.f;
    #pragma unroll
    for (int hs = 0; hs < HS; ++hs) {
        float2 v = *(const float2*)(qkv_part +
                     ((size_t)hs * NB + b) * QKV_ROWS + row0 + d0);
        x0 += v.x; x1 += v.y;
    }

    if (u < 40) {   // q or k: rmsnorm + rope
        float ss = x0 * x0 + x1 * x1;
        ss += __shfl_xor(ss, 1);
        ss += __shfl_xor(ss, 2);
        ss += __shfl_xor(ss, 4);
        ss += __shfl_xor(ss, 8);
        ss += __shfl_xor(ss, 16);
        ss += __shfl_xor(ss, 32);
        float inv = 1.0f / sqrtf(ss * (1.0f / DD) + 1e-6f);
        const float* w = (u < 32) ? qw : kw;
        x0 = x0 * inv * w[d0];
        x1 = x1 * inv * w[d0 + 1];
        // partial rope on d<64 (lanes 0..31); partner at d +/- 32 = lane^16
        float p0 = __shfl_xor(x0, 16);
        float p1 = __shfl_xor(x1, 16);
        if (lane < 32) {
            float c0 = cosb[b * ROPE_D + d0];
            float c1 = cosb[b * ROPE_D + d0 + 1];
            float s0 = sinb[b * ROPE_D + d0];
            float s1 = sinb[b * ROPE_D + d0 + 1];
            float r0 = (lane < 16) ? -p0 : p0;   // d<32: -x[d+32]; 32<=d<64: +x[d-32]
            float r1 = (lane < 16) ? -p1 : p1;
            x0 = fmaf(x0, c0, r0 * s0);
            x1 = fmaf(x1, c1, r1 * s1);
        }
    }

    if (u < 32) {
        float* q = q_ws + (size_t)b * 4096 + u * DD + d0;
        q[0] = x0; q[1] = x1;
    } else {
        int loc = out_cache_loc[b];
        int kvh = (u < 40) ? (u - 32) : (u - 40);
        float* pool = (u < 40) ? k_pool : v_pool;
        float2 val; val.x = x0; val.y = x1;
        *(float2*)(pool + (size_t)loc * (NKV * DD) + kvh * DD + d0) = val;
    }
}

// ---------------------------------------------------------------------------
// K3: flash-decode partials.  Grid (NSPLIT, NKV, NB), 256 threads.
// 16-lane group owns one KV row; lane sub covers d = sub*4..+4 (low half)
// and 64+sub*4..+4 (high half) -> every load instruction is a dense,
// contiguous 256B segment per row.  4 q-heads share the K/V row; online
// softmax in registers; merge groups via shfl, waves via LDS; write
// (m,l,o[128]) partial per (b,kvh,g,split).
// ---------------------------------------------------------------------------
__global__ __launch_bounds__(256) void attn_partial(
    const float* __restrict__ q_ws,
    const float* __restrict__ k_pool, const float* __restrict__ v_pool,
    const int* __restrict__ req_to_token,
    const int* __restrict__ req_pool_indices,
    const int* __restrict__ seq_lens,
    float* __restrict__ part_ml, float* __restrict__ part_o)
{
    const int s   = blockIdx.x;
    const int kvh = blockIdx.y;
    const int b   = blockIdx.z;
    const int t    = threadIdx.x;
    const int wave = t >> 6;
    const int lane = t & 63;
    const int sub  = lane & 15;   // d-chunk index (4 floats each half)
    const int jr   = lane >> 4;   // row-in-wave 0..3

    const int sl    = seq_lens[b];
    int start = sl - 1 - WIN; if (start < 0) start = 0;
    const int cnt  = sl - start;
    const int rows = (cnt + NSPLIT - 1) / NSPLIT;
    int j0 = start + s * rows;
    int j1 = j0 + rows; if (j1 > sl) j1 = sl;

    const int* tok_row = req_to_token + (size_t)req_pool_indices[b] * MAXCTX_;

    float4 qa[GQ], qb[GQ];
    const float* qbase = q_ws + (size_t)b * 4096 + (kvh * GQ) * DD;
    #pragma unroll
    for (int g = 0; g < GQ; ++g) {
        qa[g] = *(const float4*)(qbase + g * DD + sub * 4);
        qb[g] = *(const float4*)(qbase + g * DD + 64 + sub * 4);
    }

    float m[GQ], l[GQ], oa[GQ][8];
    #pragma unroll
    for (int g = 0; g < GQ; ++g) {
        m[g] = -1e30f; l[g] = 0.f;
        #pragma unroll
        for (int i = 0; i < 8; ++i) oa[g][i] = 0.f;
    }

    int nit = (j1 > j0) ? (j1 - j0 + 15) / 16 : 0;
    for (int it = 0; it < nit; ++it) {
        int jj = j0 + it * 16 + wave * 4 + jr;
        bool valid = jj < j1;
        int jc = valid ? jj : (j1 - 1);
        int tok = tok_row[jc];
        const float* kp = k_pool + (size_t)tok * (NKV * DD) + kvh * DD;
        float4 ka = *(const float4*)(kp + sub * 4);
        float4 kb = *(const float4*)(kp + 64 + sub * 4);

        float sc[GQ];
        #pragma unroll
        for (int g = 0; g < GQ; ++g) {
            float d = 0.f;
            d = fmaf(qa[g].x, ka.x, d); d = fmaf(qa[g].y, ka.y, d);
            d = fmaf(qa[g].z, ka.z, d); d = fmaf(qa[g].w, ka.w, d);
            d = fmaf(qb[g].x, kb.x, d); d = fmaf(qb[g].y, kb.y, d);
            d = fmaf(qb[g].z, kb.z, d); d = fmaf(qb[g].w, kb.w, d);
            sc[g] = d;
        }
        #pragma unroll
        for (int g = 0; g < GQ; ++g) {
            sc[g] += __shfl_xor(sc[g], 1);
            sc[g] += __shfl_xor(sc[g], 2);
            sc[g] += __shfl_xor(sc[g], 4);
            sc[g] += __shfl_xor(sc[g], 8);
        }

        const float* vp = v_pool + (size_t)tok * (NKV * DD) + kvh * DD;
        float4 va = *(const float4*)(vp + sub * 4);
        float4 vb = *(const float4*)(vp + 64 + sub * 4);

        #pragma unroll
        for (int g = 0; g < GQ; ++g) {
            float sv = valid ? sc[g] * SCALE_ : -2e30f;
            float nm = fmaxf(m[g], sv);
            float e  = __expf(sv - nm);
            float rs = __expf(m[g] - nm);
            m[g] = nm;
            l[g] = fmaf(l[g], rs, e);
            oa[g][0] = fmaf(oa[g][0], rs, e * va.x);
            oa[g][1] = fmaf(oa[g][1], rs, e * va.y);
            oa[g][2] = fmaf(oa[g][2], rs, e * va.z);
            oa[g][3] = fmaf(oa[g][3], rs, e * va.w);
            oa[g][4] = fmaf(oa[g][4], rs, e * vb.x);
            oa[g][5] = fmaf(oa[g][5], rs, e * vb.y);
            oa[g][6] = fmaf(oa[g][6], rs, e * vb.z);
            oa[g][7] = fmaf(oa[g][7], rs, e * vb.w);
        }
    }

    // merge 4 lane-groups (xor 16 preserves sub, then xor 32)
    #pragma unroll
    for (int off = 16; off <= 32; off <<= 1) {
        #pragma unroll
        for (int g = 0; g < GQ; ++g) {
            float om = __shfl_xor(m[g], off);
            float ol = __shfl_xor(l[g], off);
            float nM = fmaxf(m[g], om);
            float ea = __expf(m[g] - nM);
            float eb = __expf(om - nM);
            l[g] = l[g] * ea + ol * eb;
            #pragma unroll
            for (int i = 0; i < 8; ++i) {
                float oo = __shfl_xor(oa[g][i], off);
                oa[g][i] = oa[g][i] * ea + oo * eb;
            }
            m[g] = nM;
        }
    }

    __shared__ float smem[4][GQ][16][10];
    if (jr == 0) {
        #pragma unroll
        for (int g = 0; g < GQ; ++g) {
            smem[wave][g][sub][0] = m[g];
            smem[wave][g][sub][1] = l[g];
            #pragma unroll
            for (int i = 0; i < 8; ++i) smem[wave][g][sub][2 + i] = oa[g][i];
        }
    }
    __syncthreads();

    if (wave == 0) {
        int g = jr;                 // lanes cover (g, sub)
        float M = -1e30f, L = 0.f, O[8];
        #pragma unroll
        for (int i = 0; i < 8; ++i) O[i] = 0.f;
        #pragma unroll
        for (int w = 0; w < 4; ++w) {
            float mw = smem[w][g][sub][0];
            float lw = smem[w][g][sub][1];
            float nM = fmaxf(M, mw);
            float ea = __expf(M - nM);
            float eb = __expf(mw - nM);
            L = L * ea + lw * eb;
            #pragma unroll
            for (int i = 0; i < 8; ++i)
                O[i] = O[i] * ea + smem[w][g][sub][2 + i] * eb;
            M = nM;
        }
        size_t idx = (((size_t)b * NKV + kvh) * GQ + g) * NSPLIT + s;
        float2 ml; ml.x = M; ml.y = L;
        *(float2*)(part_ml + idx * 2) = ml;
        float* po = part_o + idx * 128;
        float4 o0; o0.x = O[0]; o0.y = O[1]; o0.z = O[2]; o0.w = O[3];
        float4 o1; o1.x = O[4]; o1.y = O[5]; o1.z = O[6]; o1.w = O[7];
        *(float4*)(po + sub * 4) = o0;
        *(float4*)(po + 64 + sub * 4) = o1;
    }
}

// ---------------------------------------------------------------------------
// K4: combine NSPLIT partials -> attn_comb[b][h*128+d]; also zero d_out.
// One wave per (h, b); lane holds 2 d-values (float2 path).
// ---------------------------------------------------------------------------
__global__ __launch_bounds__(64) void attn_combine(
    const float* __restrict__ part_ml, const float* __restrict__ part_o,
    float* __restrict__ attn_comb, float* __restrict__ d_out)
{
    const int h = blockIdx.x;   // 0..31  (h = kvh*GQ + g)
    const int b = blockIdx.y;
    const int lane = threadIdx.x;
    const int d0 = lane * 2;
    const size_t base = ((size_t)b * NH + h) * NSPLIT;

    float M = -1e30f;
    #pragma unroll
    for (int s = 0; s < NSPLIT; ++s)
        M = fmaxf(M, part_ml[(base + s) * 2]);

    float L = 0.f, a0 = 0.f, a1 = 0.f;
    #pragma unroll
    for (int s = 0; s < NSPLIT; ++s) {
        float2 ml = *(const float2*)(part_ml + (base + s) * 2);
        float w = __expf(ml.x - M);
        L = fmaf(ml.y, w, L);
        float2 o2 = *(const float2*)(part_o + (base + s) * 128 + d0);
        a0 = fmaf(o2.x, w, a0);
        a1 = fmaf(o2.y, w, a1);
    }
    float invL = 1.0f / L;
    float2 oc2; oc2.x = a0 * invL; oc2.y = a1 * invL;
    *(float2*)(attn_comb + (size_t)b * 4096 + h * DD + d0) = oc2;

    // zero the d_out slice this (b,h) owns (poisoned 0xAA by harness)
    float2 z2; z2.x = 0.f; z2.y = 0.f;
    *(float2*)(d_out + ((size_t)b * NH + h) * DD + d0) = z2;
}

// ---------------------------------------------------------------------------
// K5: output projection.  Same layout as K1; atomicAdd partials into d_out
// (zeroed by K4).
// ---------------------------------------------------------------------------
__global__ __launch_bounds__(256) void out_gemv(
    const float* __restrict__ attn_comb, const float* __restrict__ wo,
    float* __restrict__ out)
{
    const int rb = blockIdx.x;          // 0..63
    const int hs = blockIdx.y;          // 0..HS-1
    const int t  = threadIdx.x;
    const int b  = t & 15;
    const int oq = t >> 4;
    const int o0 = rb * 64;
    const int h0 = hs * (HID_ / HS);

    const float4* xp = (const float4*)(attn_comb + (size_t)b * HID_ + h0);
    const float4* w0 = (const float4*)(wo + (size_t)(o0 + oq) * HID_ + h0);
    const int rstride = 16 * HID_ / 4;

    float a0 = 0.f, a1 = 0.f, a2 = 0.f, a3 = 0.f;
    #pragma unroll 4
    for (int i = 0; i < (HID_ / HS) / 4; ++i) {
        float4 hv = xp[i];
        float4 wv0 = w0[i];
        float4 wv1 = w0[i + rstride];
        float4 wv2 = w0[i + 2 * rstride];
        float4 wv3 = w0[i + 3 * rstride];
        a0 = fmaf(hv.x, wv0.x, a0); a0 = fmaf(hv.y, wv0.y, a0);
        a0 = fmaf(hv.z, wv0.z, a0); a0 = fmaf(hv.w, wv0.w, a0);
        a1 = fmaf(hv.x, wv1.x, a1); a1 = fmaf(hv.y, wv1.y, a1);
        a1 = fmaf(hv.z, wv1.z, a1); a1 = fmaf(hv.w, wv1.w, a1);
        a2 = fmaf(hv.x, wv2.x, a2); a2 = fmaf(hv.y, wv2.y, a2);
        a2 = fmaf(hv.z, wv2.z, a2); a2 = fmaf(hv.w, wv2.w, a2);
        a3 = fmaf(hv.x, wv3.x, a3); a3 = fmaf(hv.y, wv3.y, a3);
        a3 = fmaf(hv.z, wv3.z, a3); a3 = fmaf(hv.w, wv3.w, a3);
    }
    float* op = out + (size_t)b * HID_ + o0 + oq;
    atomicAdd(op,      a0);
    atomicAdd(op + 16, a1);
    atomicAdd(op + 32, a2);
    atomicAdd(op + 48, a3);
}

// ---------------------------------------------------------------------------
extern "C" void kernel_launch(void* const* d_in, const int* in_sizes, int n_in,
                              void* d_out, int out_size, void* d_ws, size_t ws_size,
                              hipStream_t stream)
{
    const float* hidden  = (const float*)d_in[0];
    const float* cosb    = (const float*)d_in[1];
    const float* sinb    = (const float*)d_in[2];
    float*       k_pool  = (float*)d_in[3];   // written (scatter); harness restores
    float*       v_pool  = (float*)d_in[4];
    const float* wq      = (const float*)d_in[5];
    const float* wk      = (const float*)d_in[6];
    const float* wv      = (const float*)d_in[7];
    const float* wo      = (const float*)d_in[8];
    const float* qw      = (const float*)d_in[9];
    const float* kw      = (const float*)d_in[10];
    const int*   req2tok = (const int*)d_in[11];
    const int*   reqidx  = (const int*)d_in[12];
    const int*   seqlens = (const int*)d_in[13];
    const int*   cacheloc= (const int*)d_in[14];
    float* out = (float*)d_out;

    // workspace layout (floats), ~3.4 MB total.
    // q_ws persists K2->K3.  The union region holds qkv_part (K1->K2), then
    // is reused for part_ml/part_o (K3->K4) and attn_comb (K4->K5) -- those
    // lifetimes don't overlap qkv_part's (sum 598016 < 786432 floats).
    float* ws        = (float*)d_ws;
    float* q_ws      = ws;                                      // 65536
    float* unionA    = q_ws + (size_t)NB * 4096;
    float* qkv_part  = unionA;                                  // 786432
    float* part_ml   = unionA;                                  // 8192
    float* part_o    = part_ml + (size_t)NB * NH * NSPLIT * 2;  // 524288
    float* attn_comb = part_o + (size_t)NB * NH * NSPLIT * 128; // 65536

    qkv_gemv<<<dim3(QKV_ROWS / 64, HS), 256, 0, stream>>>(
        hidden, wq, wk, wv, qkv_part);

    norm_rope_scatter<<<dim3(NB, 48), 64, 0, stream>>>(
        qkv_part, cosb, sinb, qw, kw, cacheloc, q_ws, k_pool, v_pool);

    attn_partial<<<dim3(NSPLIT, NKV, NB), 256, 0, stream>>>(
        q_ws, k_pool, v_pool, req2tok, reqidx, seqlens, part_ml, part_o);

    attn_combine<<<dim3(NH, NB), 64, 0, stream>>>(
        part_ml, part_o, attn_comb, out);

    out_gemv<<<dim3(HID_ / 64, HS), 256, 0, stream>>>(
        attn_comb, wo, out);
}